// Round 3
// baseline (1236.449 us; speedup 1.0000x reference)
//
#include <hip/hip_runtime.h>
#include <cstdint>
#include <cstddef>

#define NN 50000
#define EE 1600000
#define D  64
#define DE 16

__device__ __forceinline__ float bf2f(unsigned short u) {
    return __uint_as_float(((unsigned)u) << 16);
}
__device__ __forceinline__ unsigned short f2bf(float f) {
    unsigned u = __float_as_uint(f);
    unsigned r = u + 0x7FFFu + ((u >> 16) & 1u);   // RNE
    return (unsigned short)(r >> 16);
}

// ---------------- tiny precompute: wae[k] = sum_c We[k][c]*ae[c], both layers
__global__ void k_wae(const float* We1, const float* ae1,
                      const float* We2, const float* ae2,
                      float* wae /*32 floats*/) {
    int t = threadIdx.x;
    if (t < 32) {
        const float* We = (t < 16) ? We1 : We2;
        const float* ae = (t < 16) ? ae1 : ae2;
        int k = t & 15;
        float acc = 0.f;
        for (int c = 0; c < D; c++) acc += We[k * D + c] * ae[c];
        wae[t] = acc;
    }
}

// ---------------- histogram of dst
__global__ __launch_bounds__(256) void k_hist(const int* dst, int* counts) {
    int e = blockIdx.x * 256 + threadIdx.x;
    if (e < EE) atomicAdd(&counts[dst[e]], 1);
}

// ---------------- 3-kernel exclusive scan over counts (chunks of 256)
__global__ __launch_bounds__(256) void k_scanA(const int* counts, int* bsum) {
    __shared__ int tmp[256];
    int t = threadIdx.x, i = blockIdx.x * 256 + t;
    tmp[t] = (i < NN) ? counts[i] : 0;
    __syncthreads();
    for (int off = 128; off; off >>= 1) {
        if (t < off) tmp[t] += tmp[t + off];
        __syncthreads();
    }
    if (t == 0) bsum[blockIdx.x] = tmp[0];
}

__global__ __launch_bounds__(256) void k_scanB(int* bsum, int nchunks) {
    __shared__ int tmp[256];
    int t = threadIdx.x;
    int v = (t < nchunks) ? bsum[t] : 0;
    tmp[t] = v; __syncthreads();
    for (int off = 1; off < 256; off <<= 1) {
        int x = (t >= off) ? tmp[t - off] : 0;
        __syncthreads();
        tmp[t] += x;
        __syncthreads();
    }
    if (t < nchunks) bsum[t] = tmp[t] - v;   // exclusive
}

__global__ __launch_bounds__(256) void k_scanC(const int* counts, const int* bsumex,
                                               int* offsets, int* cursor) {
    __shared__ int tmp[256];
    int t = threadIdx.x, i = blockIdx.x * 256 + t;
    int v = (i < NN) ? counts[i] : 0;
    tmp[t] = v; __syncthreads();
    for (int off = 1; off < 256; off <<= 1) {
        int x = (t >= off) ? tmp[t - off] : 0;
        __syncthreads();
        tmp[t] += x;
        __syncthreads();
    }
    int excl = tmp[t] - v + bsumex[blockIdx.x];
    if (i < NN) { offsets[i] = excl; cursor[i] = excl; }
}

// ---------------- scatter edges into dst-sorted records {src, eid}
__global__ __launch_bounds__(256) void k_scatter(const int* src, const int* dst,
                                                 int* cursor, int2* se) {
    int e = blockIdx.x * 256 + threadIdx.x;
    if (e >= EE) return;
    int d = dst[e];
    int pos = atomicAdd(&cursor[d], 1);
    se[pos] = make_int2(src[e], e);
}

// ---------------- per-layer: h = x@W, hs = h@a_s, hd = h@a_d
// IN_BF16: input feature dtype (layer2 reads the bf16 intermediate, in-place safe per-row)
template<int IN_BF16>
__global__ __launch_bounds__(256) void k_gemm(const void* xin, const float* W,
                                              const float* a_s, const float* a_d,
                                              unsigned short* h, float* hs, float* hd) {
    __shared__ float Wf[64][64];
    __shared__ float xs[4][64];
    int t = threadIdx.x, lane = t & 63, wv = t >> 6;
    for (int i = t; i < 4096; i += 256) Wf[i >> 6][i & 63] = W[i];
    float asl = a_s[lane];
    float adl = a_d[lane];
    __syncthreads();
    for (int n = blockIdx.x * 4 + wv; n < NN; n += gridDim.x * 4) {
        size_t idx = (size_t)n * D + lane;
        float xv = IN_BF16 ? bf2f(((const unsigned short*)xin)[idx])
                           : ((const float*)xin)[idx];
        xs[wv][lane] = xv;                 // same-wave LDS stage (in-order per-wave LDS ops)
        float acc = 0.f;
        #pragma unroll
        for (int k = 0; k < 64; k++) acc += xs[wv][k] * Wf[k][lane];
        h[idx] = f2bf(acc);                // full row read before write -> in-place safe
        float ps = acc * asl, pd = acc * adl;
        #pragma unroll
        for (int off = 32; off; off >>= 1) {
            ps += __shfl_xor(ps, off);
            pd += __shfl_xor(pd, off);
        }
        if (lane == 0) { hs[n] = ps; hd[n] = pd; }
    }
}

// ---------------- fused per-node GAT: online-softmax stats, channel-max aggregate, bias+act
// OUT_F32: layer2 writes fp32 d_out, layer1 writes bf16 intermediate
template<int OUT_F32>
__global__ __launch_bounds__(256) void k_gat(const int2* se, const int* offsets, const int* counts,
                                             const float* hs, const float* hd,
                                             const unsigned short* h, const float* ea,
                                             const float* We, const float* b,
                                             const float* wae /*16 floats for this layer*/,
                                             void* outv) {
    __shared__ float Wel[16][64];
    __shared__ float waes[16];
    int t = threadIdx.x, lane = t & 63, wv = t >> 6;
    for (int i = t; i < 1024; i += 256) Wel[i >> 6][i & 63] = We[i];
    if (t < 16) waes[t] = wae[t];
    float bl = b[lane];
    __syncthreads();

    int d = blockIdx.x * 4 + wv;           // grid is exactly NN/4
    int start = offsets[d];
    int deg = counts[d];
    float hdv = hd[d];

    // pass 1: online softmax over logits (lane = edge)
    float m = -__builtin_inff();
    float s = 0.f;
    for (int i = lane; i < deg; i += 64) {
        int2 r = se[start + i];
        const float4* rp = (const float4*)(ea + (size_t)r.y * DE);
        float4 q0 = rp[0], q1 = rp[1], q2 = rp[2], q3 = rp[3];
        float ev[16] = {q0.x, q0.y, q0.z, q0.w, q1.x, q1.y, q1.z, q1.w,
                        q2.x, q2.y, q2.z, q2.w, q3.x, q3.y, q3.z, q3.w};
        float ee = 0.f;
        #pragma unroll
        for (int j = 0; j < 16; j++) ee += ev[j] * waes[j];
        float lg = hs[r.x] + hdv + ee;
        lg = (lg >= 0.f) ? lg : 0.2f * lg;
        float mn = fmaxf(m, lg);
        s = ((m == mn) ? s : s * __expf(m - mn)) + __expf(lg - mn);
        m = mn;
    }
    // butterfly combine of (m, s); m==mn guard keeps -inf lanes NaN-free
    #pragma unroll
    for (int off = 32; off; off >>= 1) {
        float m2 = __shfl_xor(m, off);
        float s2 = __shfl_xor(s, off);
        float mn = fmaxf(m, m2);
        float sa = (m == mn) ? s : s * __expf(m - mn);
        float sb = (m2 == mn) ? s2 : s2 * __expf(m2 - mn);
        s = sa + sb;
        m = mn;
    }
    float invs = 1.0f / fmaxf(s, 1e-16f);

    // pass 2: aggregate (lane = channel), serial over this node's edges
    float acc = -__builtin_inff();
    for (int i = 0; i < deg; i++) {
        int2 r = se[start + i];
        float hsv = hs[r.x];                                    // wave-uniform broadcast load
        float eav = (lane < 16) ? ea[(size_t)r.y * DE + lane] : 0.f;
        float ej = 0.f, ee = 0.f;
        #pragma unroll
        for (int k = 0; k < 16; k++) {
            float ev = __shfl(eav, k);
            ej += ev * Wel[k][lane];
            ee += ev * waes[k];
        }
        float lg = hsv + hdv + ee;
        lg = (lg >= 0.f) ? lg : 0.2f * lg;
        float att = __expf(lg - m) * invs;
        float hv = bf2f(h[(size_t)r.x * D + lane]);
        acc = fmaxf(acc, (hv + ej) * att);
    }
    float val = (deg > 0) ? acc : 0.f;     // isfinite(out) ? out : 0
    val += bl;
    val = (val >= 0.f) ? val : 0.01f * val;
    size_t oidx = (size_t)d * D + lane;
    if (OUT_F32) ((float*)outv)[oidx] = val;
    else         ((unsigned short*)outv)[oidx] = f2bf(val);
}

extern "C" void kernel_launch(void* const* d_in, const int* in_sizes, int n_in,
                              void* d_out, int out_size, void* d_ws, size_t ws_size,
                              hipStream_t stream) {
    // reference dtypes are all float32 (+ int32 edge_index)
    const float* X   = (const float*)d_in[0];
    const int*   eix = (const int*)d_in[1];
    const float* ea  = (const float*)d_in[2];
    const float* W1  = (const float*)d_in[3];
    const float* We1 = (const float*)d_in[4];
    const float* as1 = (const float*)d_in[5];
    const float* ad1 = (const float*)d_in[6];
    const float* ae1 = (const float*)d_in[7];
    const float* b1  = (const float*)d_in[8];
    const float* W2  = (const float*)d_in[9];
    const float* We2 = (const float*)d_in[10];
    const float* as2 = (const float*)d_in[11];
    const float* ad2 = (const float*)d_in[12];
    const float* ae2 = (const float*)d_in[13];
    const float* b2  = (const float*)d_in[14];

    const int* src = eix;
    const int* dst = eix + EE;

    // workspace carve — total ~26.6 MB
    char* w = (char*)d_ws;
    int2* se = (int2*)w;                 w += (size_t)EE * 8;          // 12.8 MB
    unsigned short* hA = (unsigned short*)w; w += (size_t)NN * D * 2;  // 6.4 MB (h1)
    unsigned short* hB = (unsigned short*)w; w += (size_t)NN * D * 2;  // 6.4 MB (c1 -> h2 in-place)
    float* hs = (float*)w;               w += (size_t)NN * 4;
    float* hd = (float*)w;               w += (size_t)NN * 4;
    int* counts = (int*)w;               w += (size_t)NN * 4;
    int* offsets = (int*)w;              w += (size_t)NN * 4;
    int* cursor = (int*)w;               w += (size_t)NN * 4;
    int* bsum = (int*)w;                 w += 256 * 4;
    float* wae = (float*)w;              w += 32 * 4;

    const int nchunks = (NN + 255) / 256;   // 196

    hipMemsetAsync(counts, 0, (size_t)NN * 4, stream);
    k_wae<<<1, 64, 0, stream>>>(We1, ae1, We2, ae2, wae);
    k_hist<<<EE / 256, 256, 0, stream>>>(dst, counts);
    k_scanA<<<nchunks, 256, 0, stream>>>(counts, bsum);
    k_scanB<<<1, 256, 0, stream>>>(bsum, nchunks);
    k_scanC<<<nchunks, 256, 0, stream>>>(counts, bsum, offsets, cursor);
    k_scatter<<<EE / 256, 256, 0, stream>>>(src, dst, cursor, se);

    // layer 1
    k_gemm<0><<<1024, 256, 0, stream>>>(X, W1, as1, ad1, hA, hs, hd);
    k_gat<0><<<NN / 4, 256, 0, stream>>>(se, offsets, counts, hs, hd, hA, ea, We1, b1,
                                         wae, hB);
    // layer 2
    k_gemm<1><<<1024, 256, 0, stream>>>(hB, W2, as2, ad2, hB, hs, hd);   // in-place
    k_gat<1><<<NN / 4, 256, 0, stream>>>(se, offsets, counts, hs, hd, hB, ea, We2, b2,
                                         wae + 16, (float*)d_out);
}

// Round 4
// 688.600 us; speedup vs baseline: 1.7956x; 1.7956x over previous
//
#include <hip/hip_runtime.h>
#include <cstdint>
#include <cstddef>

#define NN 50000
#define EE 1600000
#define D  64
#define DE 16

__device__ __forceinline__ float bf2f(unsigned short u) {
    return __uint_as_float(((unsigned)u) << 16);
}
__device__ __forceinline__ unsigned short f2bf(float f) {
    unsigned u = __float_as_uint(f);
    unsigned r = u + 0x7FFFu + ((u >> 16) & 1u);   // RNE
    return (unsigned short)(r >> 16);
}

// ---------------- tiny precompute: wae[k] = sum_c We[k][c]*ae[c], both layers
__global__ void k_wae(const float* We1, const float* ae1,
                      const float* We2, const float* ae2,
                      float* wae /*32 floats*/) {
    int t = threadIdx.x;
    if (t < 32) {
        const float* We = (t < 16) ? We1 : We2;
        const float* ae = (t < 16) ? ae1 : ae2;
        int k = t & 15;
        float acc = 0.f;
        for (int c = 0; c < D; c++) acc += We[k * D + c] * ae[c];
        wae[t] = acc;
    }
}

// ---------------- histogram of dst
__global__ __launch_bounds__(256) void k_hist(const int* dst, int* counts) {
    int e = blockIdx.x * 256 + threadIdx.x;
    if (e < EE) atomicAdd(&counts[dst[e]], 1);
}

// ---------------- 3-kernel exclusive scan over counts (chunks of 256)
__global__ __launch_bounds__(256) void k_scanA(const int* counts, int* bsum) {
    __shared__ int tmp[256];
    int t = threadIdx.x, i = blockIdx.x * 256 + t;
    tmp[t] = (i < NN) ? counts[i] : 0;
    __syncthreads();
    for (int off = 128; off; off >>= 1) {
        if (t < off) tmp[t] += tmp[t + off];
        __syncthreads();
    }
    if (t == 0) bsum[blockIdx.x] = tmp[0];
}

__global__ __launch_bounds__(256) void k_scanB(int* bsum, int nchunks) {
    __shared__ int tmp[256];
    int t = threadIdx.x;
    int v = (t < nchunks) ? bsum[t] : 0;
    tmp[t] = v; __syncthreads();
    for (int off = 1; off < 256; off <<= 1) {
        int x = (t >= off) ? tmp[t - off] : 0;
        __syncthreads();
        tmp[t] += x;
        __syncthreads();
    }
    if (t < nchunks) bsum[t] = tmp[t] - v;   // exclusive
}

__global__ __launch_bounds__(256) void k_scanC(const int* counts, const int* bsumex,
                                               int* offsets, int* cursor) {
    __shared__ int tmp[256];
    int t = threadIdx.x, i = blockIdx.x * 256 + t;
    int v = (i < NN) ? counts[i] : 0;
    tmp[t] = v; __syncthreads();
    for (int off = 1; off < 256; off <<= 1) {
        int x = (t >= off) ? tmp[t - off] : 0;
        __syncthreads();
        tmp[t] += x;
        __syncthreads();
    }
    int excl = tmp[t] - v + bsumex[blockIdx.x];
    if (i < NN) { offsets[i] = excl; cursor[i] = excl; }
}

// ---------------- scatter edges into dst-sorted SoA records, folding ee = ea . (We@ae)
__global__ __launch_bounds__(256) void k_scatter(const int* src, const int* dst,
                                                 const float* ea, const float* wae,
                                                 int* cursor,
                                                 int* rsrc, int* reid,
                                                 float* ree1, float* ree2) {
    int e = blockIdx.x * 256 + threadIdx.x;
    if (e >= EE) return;
    int d = dst[e];
    const float4* rp = (const float4*)(ea + (size_t)e * DE);
    float4 q0 = rp[0], q1 = rp[1], q2 = rp[2], q3 = rp[3];
    float ev[16] = {q0.x, q0.y, q0.z, q0.w, q1.x, q1.y, q1.z, q1.w,
                    q2.x, q2.y, q2.z, q2.w, q3.x, q3.y, q3.z, q3.w};
    float e1 = 0.f, e2 = 0.f;
    #pragma unroll
    for (int j = 0; j < 16; j++) {
        e1 += ev[j] * wae[j];
        e2 += ev[j] * wae[16 + j];
    }
    int pos = atomicAdd(&cursor[d], 1);
    rsrc[pos] = src[e];
    reid[pos] = e;
    ree1[pos] = e1;
    ree2[pos] = e2;
}

// ---------------- per-layer: h = x@W, hs = h@a_s, hd = h@a_d
// IN_BF16: input feature dtype (layer2 reads the bf16 intermediate, in-place safe per-row)
template<int IN_BF16>
__global__ __launch_bounds__(256) void k_gemm(const void* xin, const float* W,
                                              const float* a_s, const float* a_d,
                                              unsigned short* h, float* hs, float* hd) {
    __shared__ float Wf[64][64];
    __shared__ float xs[4][64];
    int t = threadIdx.x, lane = t & 63, wv = t >> 6;
    for (int i = t; i < 4096; i += 256) Wf[i >> 6][i & 63] = W[i];
    float asl = a_s[lane];
    float adl = a_d[lane];
    __syncthreads();
    for (int n = blockIdx.x * 4 + wv; n < NN; n += gridDim.x * 4) {
        size_t idx = (size_t)n * D + lane;
        float xv = IN_BF16 ? bf2f(((const unsigned short*)xin)[idx])
                           : ((const float*)xin)[idx];
        xs[wv][lane] = xv;                 // same-wave LDS stage (in-order per-wave LDS ops)
        float acc = 0.f;
        #pragma unroll
        for (int k = 0; k < 64; k++) acc += xs[wv][k] * Wf[k][lane];
        h[idx] = f2bf(acc);                // full row read before write -> in-place safe
        float ps = acc * asl, pd = acc * adl;
        #pragma unroll
        for (int off = 32; off; off >>= 1) {
            ps += __shfl_xor(ps, off);
            pd += __shfl_xor(pd, off);
        }
        if (lane == 0) { hs[n] = ps; hd[n] = pd; }
    }
}

// ---------------- fused per-node GAT: online-softmax stats, channel-max aggregate, bias+act
// wave = one node. pass2: 4 groups of 16 lanes each take one edge; lane covers 4 channels.
// We held in registers (float4 x16); no LDS, no per-edge shuffles.
template<int OUT_F32>
__global__ __launch_bounds__(256) void k_gat(const int* rsrc, const int* reid, const float* ree,
                                             const int* offsets, const int* counts,
                                             const float* hs, const float* hd,
                                             const unsigned short* h, const float* ea,
                                             const float* We, const float* b,
                                             void* outv) {
    int t = threadIdx.x, lane = t & 63, wv = t >> 6;
    int g = lane >> 4, cl = lane & 15;

    // register-resident We[k][4cl .. 4cl+3]
    float4 WelR[16];
    #pragma unroll
    for (int k = 0; k < 16; k++) WelR[k] = *(const float4*)(We + k * 64 + 4 * cl);

    int d = blockIdx.x * 4 + wv;           // grid is exactly NN/4
    int start = offsets[d];
    int deg = counts[d];
    float hdv = hd[d];

    // pass 1: online softmax over logits (lane = edge)
    float m = -__builtin_inff();
    float s = 0.f;
    for (int i = lane; i < deg; i += 64) {
        int sidx = start + i;
        int sr = rsrc[sidx];
        float ee = ree[sidx];
        float lg = hs[sr] + hdv + ee;
        lg = (lg >= 0.f) ? lg : 0.2f * lg;
        float mn = fmaxf(m, lg);
        s = ((m == mn) ? s : s * __expf(m - mn)) + __expf(lg - mn);
        m = mn;
    }
    // butterfly combine of (m, s); m==mn guard keeps -inf lanes NaN-free
    #pragma unroll
    for (int off = 32; off; off >>= 1) {
        float m2 = __shfl_xor(m, off);
        float s2 = __shfl_xor(s, off);
        float mn = fmaxf(m, m2);
        float sa = (m == mn) ? s : s * __expf(m - mn);
        float sb = (m2 == mn) ? s2 : s2 * __expf(m2 - mn);
        s = sa + sb;
        m = mn;
    }
    float invs = 1.0f / fmaxf(s, 1e-16f);

    // pass 2: 4 edges per iteration (one per 16-lane group), 4 channels per lane
    float a0 = -__builtin_inff(), a1 = a0, a2 = a0, a3 = a0;
    for (int i = 0; i < deg; i += 4) {
        int j = i + g;
        bool valid = (j < deg);
        int sidx = start + (valid ? j : 0);
        int sr  = rsrc[sidx];
        int eid = reid[sidx];
        float ee = ree[sidx];
        float hsv = hs[sr];
        const float4* ep = (const float4*)(ea + (size_t)eid * DE);
        float4 q0 = ep[0], q1 = ep[1], q2 = ep[2], q3 = ep[3];
        ushort4 hv = *(const ushort4*)(h + (size_t)sr * D + 4 * cl);

        float lg = hsv + hdv + ee;
        lg = (lg >= 0.f) ? lg : 0.2f * lg;
        float att = __expf(lg - m) * invs;

        float ear[16] = {q0.x, q0.y, q0.z, q0.w, q1.x, q1.y, q1.z, q1.w,
                         q2.x, q2.y, q2.z, q2.w, q3.x, q3.y, q3.z, q3.w};
        float e0 = 0.f, e1 = 0.f, e2 = 0.f, e3 = 0.f;
        #pragma unroll
        for (int k = 0; k < 16; k++) {
            e0 += ear[k] * WelR[k].x;
            e1 += ear[k] * WelR[k].y;
            e2 += ear[k] * WelR[k].z;
            e3 += ear[k] * WelR[k].w;
        }
        float v0 = (bf2f(hv.x) + e0) * att;
        float v1 = (bf2f(hv.y) + e1) * att;
        float v2 = (bf2f(hv.z) + e2) * att;
        float v3 = (bf2f(hv.w) + e3) * att;
        if (!valid) { v0 = v1 = v2 = v3 = -__builtin_inff(); }
        a0 = fmaxf(a0, v0); a1 = fmaxf(a1, v1);
        a2 = fmaxf(a2, v2); a3 = fmaxf(a3, v3);
    }
    // combine the 4 groups (xor lanes 16, 32)
    #pragma unroll
    for (int off = 16; off <= 32; off <<= 1) {
        a0 = fmaxf(a0, __shfl_xor(a0, off));
        a1 = fmaxf(a1, __shfl_xor(a1, off));
        a2 = fmaxf(a2, __shfl_xor(a2, off));
        a3 = fmaxf(a3, __shfl_xor(a3, off));
    }

    if (g == 0) {
        float4 bl = *(const float4*)(b + 4 * cl);
        float o0 = ((deg > 0) ? a0 : 0.f) + bl.x;
        float o1 = ((deg > 0) ? a1 : 0.f) + bl.y;
        float o2 = ((deg > 0) ? a2 : 0.f) + bl.z;
        float o3 = ((deg > 0) ? a3 : 0.f) + bl.w;
        o0 = (o0 >= 0.f) ? o0 : 0.01f * o0;
        o1 = (o1 >= 0.f) ? o1 : 0.01f * o1;
        o2 = (o2 >= 0.f) ? o2 : 0.01f * o2;
        o3 = (o3 >= 0.f) ? o3 : 0.01f * o3;
        size_t oidx = (size_t)d * D + 4 * cl;
        if (OUT_F32) {
            *(float4*)((float*)outv + oidx) = make_float4(o0, o1, o2, o3);
        } else {
            ushort4 ov = {f2bf(o0), f2bf(o1), f2bf(o2), f2bf(o3)};
            *(ushort4*)((unsigned short*)outv + oidx) = ov;
        }
    }
}

extern "C" void kernel_launch(void* const* d_in, const int* in_sizes, int n_in,
                              void* d_out, int out_size, void* d_ws, size_t ws_size,
                              hipStream_t stream) {
    // reference dtypes are all float32 (+ int32 edge_index)
    const float* X   = (const float*)d_in[0];
    const int*   eix = (const int*)d_in[1];
    const float* ea  = (const float*)d_in[2];
    const float* W1  = (const float*)d_in[3];
    const float* We1 = (const float*)d_in[4];
    const float* as1 = (const float*)d_in[5];
    const float* ad1 = (const float*)d_in[6];
    const float* ae1 = (const float*)d_in[7];
    const float* b1  = (const float*)d_in[8];
    const float* W2  = (const float*)d_in[9];
    const float* We2 = (const float*)d_in[10];
    const float* as2 = (const float*)d_in[11];
    const float* ad2 = (const float*)d_in[12];
    const float* ae2 = (const float*)d_in[13];
    const float* b2  = (const float*)d_in[14];

    const int* src = eix;
    const int* dst = eix + EE;

    // workspace carve — total ~39.4 MB
    char* w = (char*)d_ws;
    int*   rsrc = (int*)w;               w += (size_t)EE * 4;          // 6.4 MB
    int*   reid = (int*)w;               w += (size_t)EE * 4;          // 6.4 MB
    float* ree1 = (float*)w;             w += (size_t)EE * 4;          // 6.4 MB
    float* ree2 = (float*)w;             w += (size_t)EE * 4;          // 6.4 MB
    unsigned short* hA = (unsigned short*)w; w += (size_t)NN * D * 2;  // 6.4 MB (h1)
    unsigned short* hB = (unsigned short*)w; w += (size_t)NN * D * 2;  // 6.4 MB (c1 -> h2 in-place)
    float* hs = (float*)w;               w += (size_t)NN * 4;
    float* hd = (float*)w;               w += (size_t)NN * 4;
    int* counts = (int*)w;               w += (size_t)NN * 4;
    int* offsets = (int*)w;              w += (size_t)NN * 4;
    int* cursor = (int*)w;               w += (size_t)NN * 4;
    int* bsum = (int*)w;                 w += 256 * 4;
    float* wae = (float*)w;              w += 32 * 4;

    const int nchunks = (NN + 255) / 256;   // 196

    hipMemsetAsync(counts, 0, (size_t)NN * 4, stream);
    k_wae<<<1, 64, 0, stream>>>(We1, ae1, We2, ae2, wae);
    k_hist<<<EE / 256, 256, 0, stream>>>(dst, counts);
    k_scanA<<<nchunks, 256, 0, stream>>>(counts, bsum);
    k_scanB<<<1, 256, 0, stream>>>(bsum, nchunks);
    k_scanC<<<nchunks, 256, 0, stream>>>(counts, bsum, offsets, cursor);
    k_scatter<<<EE / 256, 256, 0, stream>>>(src, dst, ea, wae, cursor,
                                            rsrc, reid, ree1, ree2);

    // layer 1
    k_gemm<0><<<1024, 256, 0, stream>>>(X, W1, as1, ad1, hA, hs, hd);
    k_gat<0><<<NN / 4, 256, 0, stream>>>(rsrc, reid, ree1, offsets, counts, hs, hd,
                                         hA, ea, We1, b1, hB);
    // layer 2
    k_gemm<1><<<1024, 256, 0, stream>>>(hB, W2, as2, ad2, hB, hs, hd);   // in-place
    k_gat<1><<<NN / 4, 256, 0, stream>>>(rsrc, reid, ree2, offsets, counts, hs, hd,
                                         hB, ea, We2, b2, (float*)d_out);
}